// Round 1
// baseline (1290.283 us; speedup 1.0000x reference)
//
#include <hip/hip_runtime.h>
#include <math.h>

#define BLOCK 256

__device__ __forceinline__ void sh16(float x, float y, float z, float* e) {
    float xx = x * x, yy = y * y, zz = z * z;
    float xy = x * y, yz = y * z, xz = x * z;
    e[0]  = 0.28209479177387814f;
    e[1]  = -0.48860251190291987f * y;
    e[2]  = 0.48860251190291987f * z;
    e[3]  = -0.48860251190291987f * x;
    e[4]  = 1.0925484305920792f * xy;
    e[5]  = -1.0925484305920792f * yz;
    e[6]  = 0.94617469575756f * zz - 0.31539156525252005f;
    e[7]  = -1.0925484305920792f * xz;
    e[8]  = 0.5462742152960396f * (xx - yy);
    e[9]  = 0.5900435899266435f * y * (3.0f * xx - yy);
    e[10] = 2.890611442640554f * xy * z;
    e[11] = 0.4570457994644657f * y * (4.0f * zz - xx - yy);
    e[12] = 0.3731763325901154f * z * (2.0f * zz - 3.0f * xx - 3.0f * yy);
    e[13] = 0.4570457994644657f * x * (4.0f * zz - xx - yy);
    e[14] = 1.445305721320277f * z * (xx - yy);
    e[15] = 0.5900435899266435f * x * (xx - 3.0f * yy);
}

// One point per thread. Hidden vectors live in registers (j-unrolled
// accumulators); anything needing dynamic-k indexing lives in a per-thread
// private LDS column act[row][tid] (bank = tid%32 -> conflict-free, no
// __syncthreads needed). Weights are wave-uniform const loads -> SMEM.
// LDS rows: 0..15 lenc, 16..31 denc (later overwritten by hc 0..63),
//           64..78 geo.
__global__ __launch_bounds__(BLOCK, 2) void nerf_fwd(
    const float* __restrict__ x_feat,
    const float* __restrict__ dvec,
    const float* __restrict__ lvec,
    const float* __restrict__ w_sig0,   // [32,64]
    const float* __restrict__ w_sig1,   // [64,16]
    const float* __restrict__ w_col0,   // [64,64]
    const float* __restrict__ w_col1,   // [79,64]
    const float* __restrict__ w_col2,   // [64,3]
    const float* __restrict__ w_vis0,   // [48,64]
    const float* __restrict__ w_vis1,   // [64,1]
    float* __restrict__ out, int n)
{
    __shared__ float act[79][BLOCK];   // 80,896 B -> 2 blocks/CU
    const int tid = threadIdx.x;
    const int pt = blockIdx.x * BLOCK + tid;
    if (pt >= n) return;

    const float* xrow = x_feat + (size_t)pt * 32;

    // ---------- sigma net: h = relu(x @ w_sig0) ----------
    float h[64];
    #pragma unroll
    for (int j = 0; j < 64; j++) h[j] = 0.f;
    for (int k = 0; k < 32; k++) {
        float xk = xrow[k];
        const float* wr = &w_sig0[k * 64];
        #pragma unroll
        for (int j = 0; j < 64; j++) h[j] = fmaf(xk, wr[j], h[j]);
    }
    #pragma unroll
    for (int j = 0; j < 64; j++) h[j] = fmaxf(h[j], 0.f);

    // geo = (h @ w_sig1)[:,1:16]  (no relu) -> LDS rows 64..78
    {
        float g[15];
        #pragma unroll
        for (int j = 0; j < 15; j++) g[j] = 0.f;
        #pragma unroll
        for (int k = 0; k < 64; k++) {
            #pragma unroll
            for (int j = 0; j < 15; j++)
                g[j] = fmaf(h[k], w_sig1[k * 16 + 1 + j], g[j]);
        }
        #pragma unroll
        for (int j = 0; j < 15; j++) act[64 + j][tid] = g[j];
    }

    // ---------- SH encodes -> LDS rows 0..15 (lig), 16..31 (d) ----------
    {
        float e[16];
        sh16(lvec[pt * 3 + 0], lvec[pt * 3 + 1], lvec[pt * 3 + 2], e);
        #pragma unroll
        for (int j = 0; j < 16; j++) act[j][tid] = e[j];
        sh16(dvec[pt * 3 + 0], dvec[pt * 3 + 1], dvec[pt * 3 + 2], e);
        #pragma unroll
        for (int j = 0; j < 16; j++) act[16 + j][tid] = e[j];
    }

    // ---------- vis net: hv = relu([x, lenc] @ w_vis0); vis = sigmoid(hv @ w_vis1) ----------
    float vis;
    {
        float hv[64];
        #pragma unroll
        for (int j = 0; j < 64; j++) hv[j] = 0.f;
        for (int k = 0; k < 32; k++) {
            float xk = xrow[k];
            const float* wr = &w_vis0[k * 64];
            #pragma unroll
            for (int j = 0; j < 64; j++) hv[j] = fmaf(xk, wr[j], hv[j]);
        }
        for (int k = 0; k < 16; k++) {
            float lk = act[k][tid];                 // lenc
            const float* wr = &w_vis0[(32 + k) * 64];
            #pragma unroll
            for (int j = 0; j < 64; j++) hv[j] = fmaf(lk, wr[j], hv[j]);
        }
        float a = 0.f;
        #pragma unroll
        for (int k = 0; k < 64; k++)
            a = fmaf(fmaxf(hv[k], 0.f), w_vis1[k], a);
        vis = 1.f / (1.f + expf(-a));
    }

    // ---------- color layer 0: hc = relu([x, lenc, denc] @ w_col0) ----------
    float hc[64];
    #pragma unroll
    for (int j = 0; j < 64; j++) hc[j] = 0.f;
    for (int k = 0; k < 32; k++) {
        float xk = xrow[k];
        const float* wr = &w_col0[k * 64];
        #pragma unroll
        for (int j = 0; j < 64; j++) hc[j] = fmaf(xk, wr[j], hc[j]);
    }
    for (int k = 0; k < 32; k++) {                  // rows 0..15 lenc, 16..31 denc
        float a = act[k][tid];
        const float* wr = &w_col0[(32 + k) * 64];
        #pragma unroll
        for (int j = 0; j < 64; j++) hc[j] = fmaf(a, wr[j], hc[j]);
    }
    #pragma unroll
    for (int j = 0; j < 64; j++) act[j][tid] = fmaxf(hc[j], 0.f);  // overwrite rows 0..63

    // ---------- color layer 1: h2 = relu([hc, geo] @ w_col1) ----------
    float h2[64];
    #pragma unroll
    for (int j = 0; j < 64; j++) h2[j] = 0.f;
    for (int k = 0; k < 79; k++) {                  // rows 0..63 hc, 64..78 geo
        float a = act[k][tid];
        const float* wr = &w_col1[k * 64];
        #pragma unroll
        for (int j = 0; j < 64; j++) h2[j] = fmaf(a, wr[j], h2[j]);
    }

    // ---------- color layer 2 (64x3) + relu + vis scale ----------
    float c0 = 0.f, c1 = 0.f, c2 = 0.f;
    #pragma unroll
    for (int k = 0; k < 64; k++) {
        float a = fmaxf(h2[k], 0.f);
        c0 = fmaf(a, w_col2[k * 3 + 0], c0);
        c1 = fmaf(a, w_col2[k * 3 + 1], c1);
        c2 = fmaf(a, w_col2[k * 3 + 2], c2);
    }
    float* o = out + (size_t)pt * 3;
    o[0] = fmaxf(c0, 0.f) * vis;
    o[1] = fmaxf(c1, 0.f) * vis;
    o[2] = fmaxf(c2, 0.f) * vis;
}

extern "C" void kernel_launch(void* const* d_in, const int* in_sizes, int n_in,
                              void* d_out, int out_size, void* d_ws, size_t ws_size,
                              hipStream_t stream) {
    const float* x_feat = (const float*)d_in[0];
    const float* dvec   = (const float*)d_in[1];
    const float* lvec   = (const float*)d_in[2];
    const float* w_sig0 = (const float*)d_in[3];
    const float* w_sig1 = (const float*)d_in[4];
    const float* w_col0 = (const float*)d_in[5];
    const float* w_col1 = (const float*)d_in[6];
    const float* w_col2 = (const float*)d_in[7];
    const float* w_vis0 = (const float*)d_in[8];
    const float* w_vis1 = (const float*)d_in[9];
    float* out = (float*)d_out;

    const int n = in_sizes[0] / 32;          // N points
    const int grid = (n + BLOCK - 1) / BLOCK;
    nerf_fwd<<<grid, BLOCK, 0, stream>>>(x_feat, dvec, lvec,
                                         w_sig0, w_sig1, w_col0, w_col1,
                                         w_col2, w_vis0, w_vis1, out, n);
}

// Round 2
// 332.471 us; speedup vs baseline: 3.8809x; 3.8809x over previous
//
#include <hip/hip_runtime.h>
#include <math.h>

#define BLOCK 256
#define GRID  512

typedef _Float16 half8  __attribute__((ext_vector_type(8)));
typedef _Float16 half4v __attribute__((ext_vector_type(4)));
typedef _Float16 half2v __attribute__((ext_vector_type(2)));
typedef float    f32x4  __attribute__((ext_vector_type(4)));

// Wave-synchronous LDS fence: all LDS ops drained, compiler may not reorder
// across it. No cross-wave sharing in this kernel -> no __syncthreads needed.
// 0xC07F = lgkmcnt(0), vmcnt(63), expcnt(7)  (gfx9 encoding)
#define WAVE_SYNC() do { __builtin_amdgcn_wave_barrier();              \
                         __builtin_amdgcn_s_waitcnt(0xC07F);           \
                         __builtin_amdgcn_wave_barrier(); } while (0)

__device__ __forceinline__ void sh16(float x, float y, float z, float* e) {
    float xx = x * x, yy = y * y, zz = z * z;
    float xy = x * y, yz = y * z, xz = x * z;
    e[0]  = 0.28209479177387814f;
    e[1]  = -0.48860251190291987f * y;
    e[2]  = 0.48860251190291987f * z;
    e[3]  = -0.48860251190291987f * x;
    e[4]  = 1.0925484305920792f * xy;
    e[5]  = -1.0925484305920792f * yz;
    e[6]  = 0.94617469575756f * zz - 0.31539156525252005f;
    e[7]  = -1.0925484305920792f * xz;
    e[8]  = 0.5462742152960396f * (xx - yy);
    e[9]  = 0.5900435899266435f * y * (3.0f * xx - yy);
    e[10] = 2.890611442640554f * xy * z;
    e[11] = 0.4570457994644657f * y * (4.0f * zz - xx - yy);
    e[12] = 0.3731763325901154f * z * (2.0f * zz - 3.0f * xx - 3.0f * yy);
    e[13] = 0.4570457994644657f * x * (4.0f * zz - xx - yy);
    e[14] = 1.445305721320277f * z * (xx - yy);
    e[15] = 0.5900435899266435f * x * (xx - 3.0f * yy);
}

// B fragment for mfma_f32_16x16x32_f16: lane holds B[k=(lane>>4)*8+j][n=lane&15].
// Source w is row-major [K, N0]; column nsrc. Out-of-range k or invalid n -> 0.
__device__ __forceinline__ half8 bfrag(const float* __restrict__ w, int N0,
                                       int nsrc, int k0, int Kreal, bool valid) {
    half8 r;
    #pragma unroll
    for (int j = 0; j < 8; j++) {
        int k = k0 + j;
        float v = (valid && k < Kreal) ? w[k * N0 + nsrc] : 0.f;
        r[j] = (_Float16)v;
    }
    return r;
}

// One MFMA layer: A in LDS [16][APAD] halfs, B frags in registers, K = KT*32,
// N = NT*16. Lane: m = lane&15 (A row / B col), q = lane>>4 (k-slice).
template<int KT, int NT, int APAD>
__device__ __forceinline__ void mfma_layer(const _Float16* A, const half8* B,
                                           f32x4* acc, int m, int q) {
    const f32x4 zero = {0.f, 0.f, 0.f, 0.f};
    #pragma unroll
    for (int nt = 0; nt < NT; nt++) acc[nt] = zero;
    #pragma unroll
    for (int kt = 0; kt < KT; kt++) {
        half8 a = *(const half8*)(A + m * APAD + kt * 32 + q * 8);
        #pragma unroll
        for (int nt = 0; nt < NT; nt++)
            acc[nt] = __builtin_amdgcn_mfma_f32_16x16x32_f16(
                a, B[nt * KT + kt], acc[nt], 0, 0, 0);
    }
}

__global__ __launch_bounds__(BLOCK, 2) void nerf_mfma(
    const float* __restrict__ x_feat,
    const float* __restrict__ dvec,
    const float* __restrict__ lvec,
    const float* __restrict__ w_sig0,   // [32,64]
    const float* __restrict__ w_sig1,   // [64,16]
    const float* __restrict__ w_col0,   // [64,64]
    const float* __restrict__ w_col1,   // [79,64]
    const float* __restrict__ w_col2,   // [64,3]
    const float* __restrict__ w_vis0,   // [48,64]
    const float* __restrict__ w_vis1,   // [64,1]
    float* __restrict__ out, int n)
{
    // Per-wave activation buffers. Strides 72/104 halfs -> 144/208 B row
    // stride -> 16B-aligned b128 reads, 2-way bank aliasing only (free).
    __shared__ alignas(16) _Float16 sA[4][16][72];   // [x|lenc|denc]
    __shared__ alignas(16) _Float16 sB[4][16][72];   // h / hv / h2
    __shared__ alignas(16) _Float16 sC[4][16][104];  // [hc|geo|pad]
    __shared__ float sVis[4][16];
    __shared__ float sOut[4][48];

    const int tid  = threadIdx.x;
    const int wv   = tid >> 6;
    const int lane = tid & 63;
    const int m    = lane & 15;
    const int q    = lane >> 4;

    _Float16* A_ = &sA[wv][0][0];
    _Float16* B_ = &sB[wv][0][0];
    _Float16* C_ = &sC[wv][0][0];

    // ---- preload all weight fragments into registers (loop-invariant) ----
    // 38 frags x 4 VGPR = 152 VGPR.
    half8 Bsig0[4], Bsig1[2], Bcol0[8], Bvis0[8], Bvis1[2], Bcol1[12], Bcol2[2];
    #pragma unroll
    for (int nt = 0; nt < 4; nt++)
        Bsig0[nt] = bfrag(w_sig0, 64, nt * 16 + m, q * 8, 32, true);
    #pragma unroll
    for (int kt = 0; kt < 2; kt++)   // geo col n <- w_sig1 col n+1; row 15 = 0
        Bsig1[kt] = bfrag(w_sig1, 16, m + 1, kt * 32 + q * 8, 64, m < 15);
    #pragma unroll
    for (int nt = 0; nt < 4; nt++)
        #pragma unroll
        for (int kt = 0; kt < 2; kt++)
            Bcol0[nt * 2 + kt] = bfrag(w_col0, 64, nt * 16 + m, kt * 32 + q * 8, 64, true);
    #pragma unroll
    for (int nt = 0; nt < 4; nt++)
        #pragma unroll
        for (int kt = 0; kt < 2; kt++)   // k rows 48..63 zero (act has denc there)
            Bvis0[nt * 2 + kt] = bfrag(w_vis0, 64, nt * 16 + m, kt * 32 + q * 8, 48, true);
    #pragma unroll
    for (int kt = 0; kt < 2; kt++)
        Bvis1[kt] = bfrag(w_vis1, 1, 0, kt * 32 + q * 8, 64, m == 0);
    #pragma unroll
    for (int nt = 0; nt < 4; nt++)
        #pragma unroll
        for (int kt = 0; kt < 3; kt++)   // K=79, rows 79..95 zero
            Bcol1[nt * 3 + kt] = bfrag(w_col1, 64, nt * 16 + m, kt * 32 + q * 8, 79, true);
    #pragma unroll
    for (int kt = 0; kt < 2; kt++)
        Bcol2[kt] = bfrag(w_col2, 3, m, kt * 32 + q * 8, 64, m < 3);

    // zero sC pad cols 80..95 once (never written in the loop)
    {
        half4v z4 = {(_Float16)0.f, (_Float16)0.f, (_Float16)0.f, (_Float16)0.f};
        *(half4v*)(&sC[wv][lane >> 2][80 + (lane & 3) * 4]) = z4;
    }

    const int ntiles = n >> 6;   // 64 points per block-tile (16 per wave)
    for (int t = blockIdx.x; t < ntiles; t += gridDim.x) {
        const int pbase = (t << 6) + wv * 16;

        // ---- stage x: 16 rows x 32 cols fp32 -> f16 into sA cols 0..31 ----
        {
            const int mr = lane >> 2, c = lane & 3;
            const float* xp = x_feat + (size_t)(pbase + mr) * 32 + c * 8;
            const float4* xv = (const float4*)xp;
            float4 v0 = xv[0], v1 = xv[1];
            half8 hx;
            hx[0] = (_Float16)v0.x; hx[1] = (_Float16)v0.y;
            hx[2] = (_Float16)v0.z; hx[3] = (_Float16)v0.w;
            hx[4] = (_Float16)v1.x; hx[5] = (_Float16)v1.y;
            hx[6] = (_Float16)v1.z; hx[7] = (_Float16)v1.w;
            *(half8*)(A_ + mr * 72 + c * 8) = hx;
        }
        // ---- SH encodes: lanes 0-15 lig -> cols 32..47, 16-31 d -> 48..63 ----
        if (lane < 32) {
            const int p = lane & 15;
            const bool isl = lane < 16;
            const float* vv = (isl ? lvec : dvec) + (size_t)(pbase + p) * 3;
            float e[16];
            sh16(vv[0], vv[1], vv[2], e);
            const int cb = isl ? 32 : 48;
            #pragma unroll
            for (int u = 0; u < 8; u++) {
                half2v pr;
                pr[0] = (_Float16)e[2 * u];
                pr[1] = (_Float16)e[2 * u + 1];
                *(half2v*)(A_ + p * 72 + cb + 2 * u) = pr;
            }
        }
        WAVE_SYNC();

        f32x4 acc[4];

        // sig0: h = relu(x @ w_sig0), K=32 -> sB
        mfma_layer<1, 4, 72>(A_, Bsig0, acc, m, q);
        #pragma unroll
        for (int nt = 0; nt < 4; nt++)
            #pragma unroll
            for (int r = 0; r < 4; r++)
                B_[(q * 4 + r) * 72 + nt * 16 + m] = (_Float16)fmaxf(acc[nt][r], 0.f);
        WAVE_SYNC();

        // geo = h @ w_sig1[:,1:16] (no relu) -> sC cols 64..79 (col 79 = 0)
        mfma_layer<2, 1, 72>(B_, Bsig1, acc, m, q);
        #pragma unroll
        for (int r = 0; r < 4; r++)
            C_[(q * 4 + r) * 104 + 64 + m] = (_Float16)acc[0][r];

        // col0: hc = relu([x|lenc|denc] @ w_col0), K=64 -> sC cols 0..63
        mfma_layer<2, 4, 72>(A_, Bcol0, acc, m, q);
        #pragma unroll
        for (int nt = 0; nt < 4; nt++)
            #pragma unroll
            for (int r = 0; r < 4; r++)
                C_[(q * 4 + r) * 104 + nt * 16 + m] = (_Float16)fmaxf(acc[nt][r], 0.f);

        // vis0: hv = relu([x|lenc] @ w_vis0) (w rows 48..63 = 0) -> sB
        mfma_layer<2, 4, 72>(A_, Bvis0, acc, m, q);
        #pragma unroll
        for (int nt = 0; nt < 4; nt++)
            #pragma unroll
            for (int r = 0; r < 4; r++)
                B_[(q * 4 + r) * 72 + nt * 16 + m] = (_Float16)fmaxf(acc[nt][r], 0.f);
        WAVE_SYNC();

        // vis1 + sigmoid: only col 0 meaningful
        mfma_layer<2, 1, 72>(B_, Bvis1, acc, m, q);
        if (m == 0) {
            #pragma unroll
            for (int r = 0; r < 4; r++)
                sVis[wv][q * 4 + r] = 1.f / (1.f + expf(-acc[0][r]));
        }

        // col1: h2 = relu([hc|geo] @ w_col1), K=96 (rows 79+ zero) -> sB
        mfma_layer<3, 4, 104>(C_, Bcol1, acc, m, q);
        #pragma unroll
        for (int nt = 0; nt < 4; nt++)
            #pragma unroll
            for (int r = 0; r < 4; r++)
                B_[(q * 4 + r) * 72 + nt * 16 + m] = (_Float16)fmaxf(acc[nt][r], 0.f);
        WAVE_SYNC();

        // col2: color = relu(h2 @ w_col2) * vis -> sOut (cols 0..2 valid)
        mfma_layer<2, 1, 72>(B_, Bcol2, acc, m, q);
        if (m < 3) {
            #pragma unroll
            for (int r = 0; r < 4; r++)
                sOut[wv][(q * 4 + r) * 3 + m] = fmaxf(acc[0][r], 0.f) * sVis[wv][q * 4 + r];
        }
        WAVE_SYNC();

        if (lane < 48)
            out[(size_t)pbase * 3 + lane] = sOut[wv][lane];
    }
}

extern "C" void kernel_launch(void* const* d_in, const int* in_sizes, int n_in,
                              void* d_out, int out_size, void* d_ws, size_t ws_size,
                              hipStream_t stream) {
    const float* x_feat = (const float*)d_in[0];
    const float* dvec   = (const float*)d_in[1];
    const float* lvec   = (const float*)d_in[2];
    const float* w_sig0 = (const float*)d_in[3];
    const float* w_sig1 = (const float*)d_in[4];
    const float* w_col0 = (const float*)d_in[5];
    const float* w_col1 = (const float*)d_in[6];
    const float* w_col2 = (const float*)d_in[7];
    const float* w_vis0 = (const float*)d_in[8];
    const float* w_vis1 = (const float*)d_in[9];
    float* out = (float*)d_out;

    const int n = in_sizes[0] / 32;   // N points (1048576: multiple of 64)
    nerf_mfma<<<GRID, BLOCK, 0, stream>>>(x_feat, dvec, lvec,
                                          w_sig0, w_sig1, w_col0, w_col1,
                                          w_col2, w_vis0, w_vis1, out, n);
}

// Round 3
// 314.272 us; speedup vs baseline: 4.1056x; 1.0579x over previous
//
#include <hip/hip_runtime.h>
#include <math.h>

#define BLOCK 256
#define GRID  512

typedef _Float16 half8  __attribute__((ext_vector_type(8)));
typedef _Float16 half4v __attribute__((ext_vector_type(4)));
typedef float    f32x4  __attribute__((ext_vector_type(4)));

// Wave-synchronous LDS fence (no cross-wave sharing -> no __syncthreads).
// 0xC07F = lgkmcnt(0), vmcnt(63), expcnt(7)
#define WAVE_SYNC() do { __builtin_amdgcn_wave_barrier();              \
                         __builtin_amdgcn_s_waitcnt(0xC07F);           \
                         __builtin_amdgcn_wave_barrier(); } while (0)

__device__ __forceinline__ void sh16(float x, float y, float z, float* e) {
    float xx = x * x, yy = y * y, zz = z * z;
    float xy = x * y, yz = y * z, xz = x * z;
    e[0]  = 0.28209479177387814f;
    e[1]  = -0.48860251190291987f * y;
    e[2]  = 0.48860251190291987f * z;
    e[3]  = -0.48860251190291987f * x;
    e[4]  = 1.0925484305920792f * xy;
    e[5]  = -1.0925484305920792f * yz;
    e[6]  = 0.94617469575756f * zz - 0.31539156525252005f;
    e[7]  = -1.0925484305920792f * xz;
    e[8]  = 0.5462742152960396f * (xx - yy);
    e[9]  = 0.5900435899266435f * y * (3.0f * xx - yy);
    e[10] = 2.890611442640554f * xy * z;
    e[11] = 0.4570457994644657f * y * (4.0f * zz - xx - yy);
    e[12] = 0.3731763325901154f * z * (2.0f * zz - 3.0f * xx - 3.0f * yy);
    e[13] = 0.4570457994644657f * x * (4.0f * zz - xx - yy);
    e[14] = 1.445305721320277f * z * (xx - yy);
    e[15] = 0.5900435899266435f * x * (xx - 3.0f * yy);
}

// Weight fragment (A operand): lane holds A[i=lane&15][k=(lane>>4)*8+j] with
// A[i][k] = w[k][nsrc(i)].  w row-major [K, N0].
__device__ __forceinline__ half8 bfrag(const float* __restrict__ w, int N0,
                                       int nsrc, int k0, int Kreal, bool valid) {
    half8 r;
    #pragma unroll
    for (int j = 0; j < 8; j++) {
        int k = k0 + j;
        float v = (valid && k < Kreal) ? w[k * N0 + nsrc] : 0.f;
        r[j] = (_Float16)v;
    }
    return r;
}

// C = W @ actT : A = weight frags (registers), B = activation frags from LDS
// (act stored [point][feature], feature-contiguous). Lane: m = lane&15
// (point col / weight out-row), q = lane>>4 (k-slice).
// Output: lane holds C[feat = nt*16 + q*4 + r][point m].
template<int KT, int NT, int APAD>
__device__ __forceinline__ void mfma_layer(const _Float16* act, const half8* W,
                                           f32x4* acc, int m, int q) {
    const f32x4 zero = {0.f, 0.f, 0.f, 0.f};
    #pragma unroll
    for (int nt = 0; nt < NT; nt++) acc[nt] = zero;
    #pragma unroll
    for (int kt = 0; kt < KT; kt++) {
        half8 b = *(const half8*)(act + m * APAD + kt * 32 + q * 8);
        #pragma unroll
        for (int nt = 0; nt < NT; nt++)
            acc[nt] = __builtin_amdgcn_mfma_f32_16x16x32_f16(
                W[nt * KT + kt], b, acc[nt], 0, 0, 0);
    }
}

// Packed epilogue: lane writes 4 consecutive features of point m as one b64.
template<int NT, int APAD, bool RELU>
__device__ __forceinline__ void store_act(_Float16* dst, const f32x4* acc,
                                          int m, int q, int colbase) {
    #pragma unroll
    for (int nt = 0; nt < NT; nt++) {
        half4v h;
        #pragma unroll
        for (int r = 0; r < 4; r++) {
            float v = acc[nt][r];
            if (RELU) v = fmaxf(v, 0.f);
            h[r] = (_Float16)v;
        }
        *(half4v*)(dst + m * APAD + colbase + nt * 16 + q * 4) = h;
    }
}

__global__ __launch_bounds__(BLOCK, 2) void nerf_mfma(
    const float* __restrict__ x_feat,
    const float* __restrict__ dvec,
    const float* __restrict__ lvec,
    const float* __restrict__ w_sig0,   // [32,64]
    const float* __restrict__ w_sig1,   // [64,16]
    const float* __restrict__ w_col0,   // [64,64]
    const float* __restrict__ w_col1,   // [79,64]
    const float* __restrict__ w_col2,   // [64,3]
    const float* __restrict__ w_vis0,   // [48,64]
    const float* __restrict__ w_vis1,   // [64,1]
    float* __restrict__ out, int n)
{
    // Per-wave, 2 slots (two independent 16-point tiles in flight per wave).
    __shared__ alignas(16) _Float16 sA[4][2][16][72];   // [x|lenc|denc] / h2
    __shared__ alignas(16) _Float16 sB[4][2][16][72];   // h / hv
    __shared__ alignas(16) _Float16 sC[4][2][16][104];  // [hc|geo|pad]
    __shared__ float sOut[4][2][48];
    // total: 18432+18432+26624+1536 = 65024 B

    const int tid  = threadIdx.x;
    const int wv   = tid >> 6;
    const int lane = tid & 63;
    const int m    = lane & 15;
    const int q    = lane >> 4;

    // ---- preload all weight fragments (loop-invariant; compiler -> AGPRs) ----
    half8 Wsig0[4], Wsig1[2], Wcol0[8], Wvis0[8], Wvis1[2], Wcol1[12], Wcol2[2];
    #pragma unroll
    for (int nt = 0; nt < 4; nt++)
        Wsig0[nt] = bfrag(w_sig0, 64, nt * 16 + m, q * 8, 32, true);
    #pragma unroll
    for (int kt = 0; kt < 2; kt++)   // geo i <- w_sig1 col i+1; i=15 -> 0
        Wsig1[kt] = bfrag(w_sig1, 16, m + 1, kt * 32 + q * 8, 64, m < 15);
    #pragma unroll
    for (int nt = 0; nt < 4; nt++)
        #pragma unroll
        for (int kt = 0; kt < 2; kt++)
            Wcol0[nt * 2 + kt] = bfrag(w_col0, 64, nt * 16 + m, kt * 32 + q * 8, 64, true);
    #pragma unroll
    for (int nt = 0; nt < 4; nt++)
        #pragma unroll
        for (int kt = 0; kt < 2; kt++)   // k rows 48..63 zero (denc unused)
            Wvis0[nt * 2 + kt] = bfrag(w_vis0, 64, nt * 16 + m, kt * 32 + q * 8, 48, true);
    #pragma unroll
    for (int kt = 0; kt < 2; kt++)
        Wvis1[kt] = bfrag(w_vis1, 1, 0, kt * 32 + q * 8, 64, m == 0);
    #pragma unroll
    for (int nt = 0; nt < 4; nt++)
        #pragma unroll
        for (int kt = 0; kt < 3; kt++)   // K=79, rows 79..95 zero
            Wcol1[nt * 3 + kt] = bfrag(w_col1, 64, nt * 16 + m, kt * 32 + q * 8, 79, true);
    #pragma unroll
    for (int kt = 0; kt < 2; kt++)
        Wcol2[kt] = bfrag(w_col2, 3, m, kt * 32 + q * 8, 64, m < 3);

    // zero sC pad cols 80..95 (never written in the loop; col1 reads them)
    #pragma unroll
    for (int s = 0; s < 2; s++) {
        half4v z4 = {(_Float16)0.f, (_Float16)0.f, (_Float16)0.f, (_Float16)0.f};
        *(half4v*)(&sC[wv][s][lane >> 2][80 + (lane & 3) * 4]) = z4;
    }

    const int ntiles = n >> 7;   // 128 points per block-tile (32 per wave)
    for (int t = blockIdx.x; t < ntiles; t += gridDim.x) {
        const int pb0 = (t << 7) + wv * 32;

        // ---- stage x + SH for both slots ----
        #pragma unroll
        for (int s = 0; s < 2; s++) {
            const int pbase = pb0 + s * 16;
            _Float16* A_ = &sA[wv][s][0][0];
            {   // x: 16 rows x 32 f32 -> f16 cols 0..31
                const int mr = lane >> 2, c = lane & 3;
                const float4* xv = (const float4*)(x_feat + (size_t)(pbase + mr) * 32 + c * 8);
                float4 v0 = xv[0], v1 = xv[1];
                half8 hx;
                hx[0] = (_Float16)v0.x; hx[1] = (_Float16)v0.y;
                hx[2] = (_Float16)v0.z; hx[3] = (_Float16)v0.w;
                hx[4] = (_Float16)v1.x; hx[5] = (_Float16)v1.y;
                hx[6] = (_Float16)v1.z; hx[7] = (_Float16)v1.w;
                *(half8*)(A_ + mr * 72 + c * 8) = hx;
            }
            if (lane < 32) {   // SH: lanes 0-15 lig -> cols 32..47, 16-31 d -> 48..63
                const int p = lane & 15;
                const bool isl = lane < 16;
                const float* vv = (isl ? lvec : dvec) + (size_t)(pbase + p) * 3;
                float e[16];
                sh16(vv[0], vv[1], vv[2], e);
                const int cb = isl ? 32 : 48;
                half8 h0, h1;
                #pragma unroll
                for (int u = 0; u < 8; u++) { h0[u] = (_Float16)e[u]; h1[u] = (_Float16)e[8 + u]; }
                *(half8*)(A_ + p * 72 + cb) = h0;
                *(half8*)(A_ + p * 72 + cb + 8) = h1;
            }
        }
        WAVE_SYNC();

        f32x4 acc[2][4];
        float vis[2];

        // sig0: h = relu(x @ w_sig0) -> sB
        #pragma unroll
        for (int s = 0; s < 2; s++) {
            mfma_layer<1, 4, 72>(&sA[wv][s][0][0], Wsig0, acc[s], m, q);
            store_act<4, 72, true>(&sB[wv][s][0][0], acc[s], m, q, 0);
        }
        WAVE_SYNC();

        // geo = h @ w_sig1[:,1:16] -> sC cols 64..79 ; col0 -> sC cols 0..63
        #pragma unroll
        for (int s = 0; s < 2; s++) {
            mfma_layer<2, 1, 72>(&sB[wv][s][0][0], Wsig1, acc[s], m, q);
            store_act<1, 104, false>(&sC[wv][s][0][0], acc[s], m, q, 64);
            mfma_layer<2, 4, 72>(&sA[wv][s][0][0], Wcol0, acc[s], m, q);
            store_act<4, 104, true>(&sC[wv][s][0][0], acc[s], m, q, 0);
        }
        WAVE_SYNC();   // sB (h) reads done -> reusable

        // vis0: hv = relu([x|lenc] @ w_vis0) -> sB
        #pragma unroll
        for (int s = 0; s < 2; s++) {
            mfma_layer<2, 4, 72>(&sA[wv][s][0][0], Wvis0, acc[s], m, q);
            store_act<4, 72, true>(&sB[wv][s][0][0], acc[s], m, q, 0);
        }
        WAVE_SYNC();

        // vis1 + sigmoid (row 0 -> q==0 lanes, point m);  col1 -> sA (h2)
        #pragma unroll
        for (int s = 0; s < 2; s++) {
            mfma_layer<2, 1, 72>(&sB[wv][s][0][0], Wvis1, acc[s], m, q);
            if (q == 0) vis[s] = 1.f / (1.f + expf(-acc[s][0][0]));
            mfma_layer<3, 4, 104>(&sC[wv][s][0][0], Wcol1, acc[s], m, q);
            store_act<4, 72, true>(&sA[wv][s][0][0], acc[s], m, q, 0);
        }
        WAVE_SYNC();

        // col2: color = relu(h2 @ w_col2) * vis ; rows 0..2 live in q==0 lanes
        #pragma unroll
        for (int s = 0; s < 2; s++) {
            mfma_layer<2, 1, 72>(&sA[wv][s][0][0], Wcol2, acc[s], m, q);
            if (q == 0) {
                #pragma unroll
                for (int r = 0; r < 3; r++)
                    sOut[wv][s][m * 3 + r] = fmaxf(acc[s][0][r], 0.f) * vis[s];
            }
        }
        WAVE_SYNC();

        #pragma unroll
        for (int s = 0; s < 2; s++)
            if (lane < 48)
                out[(size_t)(pb0 + s * 16) * 3 + lane] = sOut[wv][s][lane];
        WAVE_SYNC();   // sOut/sA safe for next iteration
    }
}

extern "C" void kernel_launch(void* const* d_in, const int* in_sizes, int n_in,
                              void* d_out, int out_size, void* d_ws, size_t ws_size,
                              hipStream_t stream) {
    const float* x_feat = (const float*)d_in[0];
    const float* dvec   = (const float*)d_in[1];
    const float* lvec   = (const float*)d_in[2];
    const float* w_sig0 = (const float*)d_in[3];
    const float* w_sig1 = (const float*)d_in[4];
    const float* w_col0 = (const float*)d_in[5];
    const float* w_col1 = (const float*)d_in[6];
    const float* w_col2 = (const float*)d_in[7];
    const float* w_vis0 = (const float*)d_in[8];
    const float* w_vis1 = (const float*)d_in[9];
    float* out = (float*)d_out;

    const int n = in_sizes[0] / 32;   // N points (1048576: multiple of 128)
    nerf_mfma<<<GRID, BLOCK, 0, stream>>>(x_feat, dvec, lvec,
                                          w_sig0, w_sig1, w_col0, w_col1,
                                          w_col2, w_vis0, w_vis1, out, n);
}

// Round 4
// 292.023 us; speedup vs baseline: 4.4184x; 1.0762x over previous
//
#include <hip/hip_runtime.h>
#include <math.h>

#define BLOCK 256
#define GRID  512

typedef _Float16 half8 __attribute__((ext_vector_type(8)));
typedef float    f32x4 __attribute__((ext_vector_type(4)));

// Output-column permutation: producer layer writes logical out-feat
// phi(nt, i) into MFMA out-slot (nt, i). Then lane (m,q)'s C quads
// (acc[nt][r] = feat phi(nt, q*4+r)) packed pairwise give exactly the
// consumer B-frag halves (feats kt*32 + q*8 + j, j=0..7) with ZERO data
// movement: activations chain lane-locally through registers.
__device__ __forceinline__ int phi(int nt, int m) {
    return ((nt >> 1) << 5) + ((m >> 2) << 3) + ((nt & 1) << 2) + (m & 3);
}

// A-operand weight fragment: lane (m,q) holds A[i=m][k=q*8+j] = w[k][nsrc].
// w row-major [Kreal, N0]; out-of-range k or !valid -> 0.
__device__ __forceinline__ half8 bfragW(const float* __restrict__ w, int N0,
                                        int nsrc, int k0, int Kreal, bool valid) {
    half8 r;
    #pragma unroll
    for (int j = 0; j < 8; j++) {
        int k = k0 + j;
        float v = (valid && k < Kreal) ? w[k * N0 + nsrc] : 0.f;
        r[j] = (_Float16)v;
    }
    return r;
}

__device__ __forceinline__ half8 packrelu(f32x4 a, f32x4 b) {
    half8 h;
    #pragma unroll
    for (int r = 0; r < 4; r++) {
        h[r]     = (_Float16)fmaxf(a[r], 0.f);
        h[4 + r] = (_Float16)fmaxf(b[r], 0.f);
    }
    return h;
}

__device__ __forceinline__ half8 packraw(f32x4 a, f32x4 b) {
    half8 h;
    #pragma unroll
    for (int r = 0; r < 4; r++) {
        h[r]     = (_Float16)a[r];
        h[4 + r] = (_Float16)b[r];
    }
    return h;
}

__device__ __forceinline__ void sh16(float x, float y, float z, float* e) {
    float xx = x * x, yy = y * y, zz = z * z;
    float xy = x * y, yz = y * z, xz = x * z;
    e[0]  = 0.28209479177387814f;
    e[1]  = -0.48860251190291987f * y;
    e[2]  = 0.48860251190291987f * z;
    e[3]  = -0.48860251190291987f * x;
    e[4]  = 1.0925484305920792f * xy;
    e[5]  = -1.0925484305920792f * yz;
    e[6]  = 0.94617469575756f * zz - 0.31539156525252005f;
    e[7]  = -1.0925484305920792f * xz;
    e[8]  = 0.5462742152960396f * (xx - yy);
    e[9]  = 0.5900435899266435f * y * (3.0f * xx - yy);
    e[10] = 2.890611442640554f * xy * z;
    e[11] = 0.4570457994644657f * y * (4.0f * zz - xx - yy);
    e[12] = 0.3731763325901154f * z * (2.0f * zz - 3.0f * xx - 3.0f * yy);
    e[13] = 0.4570457994644657f * x * (4.0f * zz - xx - yy);
    e[14] = 1.445305721320277f * z * (xx - yy);
    e[15] = 0.5900435899266435f * x * (xx - 3.0f * yy);
}

#define MFMA(A, B, C) __builtin_amdgcn_mfma_f32_16x16x32_f16((A), (B), (C), 0, 0, 0)

__global__ __launch_bounds__(BLOCK, 2) void nerf_reg(
    const float* __restrict__ x_feat,
    const float* __restrict__ dvec,
    const float* __restrict__ lvec,
    const float* __restrict__ w_sig0,   // [32,64]
    const float* __restrict__ w_sig1,   // [64,16]
    const float* __restrict__ w_col0,   // [64,64]
    const float* __restrict__ w_col1,   // [79,64]
    const float* __restrict__ w_col2,   // [64,3]
    const float* __restrict__ w_vis0,   // [48,64]
    const float* __restrict__ w_vis1,   // [64,1]
    float* __restrict__ out, int n)
{
    const int tid  = threadIdx.x;
    const int wv   = tid >> 6;
    const int lane = tid & 63;
    const int m    = lane & 15;
    const int q    = lane >> 4;

    // ---------- preload all weight frags (loop-invariant -> AGPRs) ----------
    half8 Wsig0[4], Wcol0[8], Wvis0[8], Wsig1[4], Wvis1[2], Wcol1[12], Wcol2[2];
    #pragma unroll
    for (int nt = 0; nt < 4; nt++)
        Wsig0[nt] = bfragW(w_sig0, 64, phi(nt, m), q * 8, 32, true);
    #pragma unroll
    for (int nt = 0; nt < 4; nt++)
        #pragma unroll
        for (int kt = 0; kt < 2; kt++)
            Wcol0[nt * 2 + kt] = bfragW(w_col0, 64, phi(nt, m), kt * 32 + q * 8, 64, true);
    #pragma unroll
    for (int nt = 0; nt < 4; nt++)
        #pragma unroll
        for (int kt = 0; kt < 2; kt++)   // k rows 48..63 zero (denc unused by vis)
            Wvis0[nt * 2 + kt] = bfragW(w_vis0, 64, phi(nt, m), kt * 32 + q * 8, 48, true);
    // sig1 -> geo, widened to 32 out-cols with zero pads so that lanes q<2
    // hold geo[q*8+j] and lanes q>=2 hold zeros (col1 kt=2 layout).
    #pragma unroll
    for (int nt = 0; nt < 2; nt++)
        #pragma unroll
        for (int kt = 0; kt < 2; kt++) {
            int g = ((m >> 2) << 3) + ((nt & 1) << 2) + (m & 3);  // geo feat
            bool valid = ((m >> 2) < 2) && (g < 15);
            Wsig1[nt * 2 + kt] = bfragW(w_sig1, 16, g + 1, kt * 32 + q * 8, 64, valid);
        }
    #pragma unroll
    for (int kt = 0; kt < 2; kt++)
        Wvis1[kt] = bfragW(w_vis1, 1, 0, kt * 32 + q * 8, 64, m == 0);
    #pragma unroll
    for (int nt = 0; nt < 4; nt++)
        #pragma unroll
        for (int kt = 0; kt < 3; kt++)   // K=79; rows 79..95 zero
            Wcol1[nt * 3 + kt] = bfragW(w_col1, 64, phi(nt, m), kt * 32 + q * 8, 79, true);
    #pragma unroll
    for (int kt = 0; kt < 2; kt++)
        Wcol2[kt] = bfragW(w_col2, 3, m, kt * 32 + q * 8, 64, m < 3);

    const f32x4 z = {0.f, 0.f, 0.f, 0.f};
    const int ntiles = n >> 6;           // 64 points per block, 16 per wave
    for (int t = blockIdx.x; t < ntiles; t += GRID) {
        const int pt = (t << 6) + wv * 16 + m;

        // ---- input frag kt=0: x[m][q*8 .. q*8+7] straight from global ----
        const float4* xv = (const float4*)(x_feat + (size_t)pt * 32 + q * 8);
        float4 v0 = xv[0], v1 = xv[1];
        half8 fI0;
        fI0[0] = (_Float16)v0.x; fI0[1] = (_Float16)v0.y;
        fI0[2] = (_Float16)v0.z; fI0[3] = (_Float16)v0.w;
        fI0[4] = (_Float16)v1.x; fI0[5] = (_Float16)v1.y;
        fI0[6] = (_Float16)v1.z; fI0[7] = (_Float16)v1.w;

        // ---- input frag kt=1: SH in-lane. q<2 -> lenc, q>=2 -> denc;
        //      (q&1)==0 -> comps 0..7, ==1 -> comps 8..15 ----
        const float* vv = (q < 2 ? lvec : dvec) + (size_t)pt * 3;
        float e[16];
        sh16(vv[0], vv[1], vv[2], e);
        half8 lo, hi;
        #pragma unroll
        for (int u = 0; u < 8; u++) {
            lo[u] = (_Float16)e[u];
            hi[u] = (_Float16)e[8 + u];
        }
        half8 fI1 = (q & 1) ? hi : lo;

        // ---- sig0: h = relu(x @ w_sig0), K=32 ----
        f32x4 a0 = z, a1 = z, a2 = z, a3 = z;
        a0 = MFMA(Wsig0[0], fI0, a0);
        a1 = MFMA(Wsig0[1], fI0, a1);
        a2 = MFMA(Wsig0[2], fI0, a2);
        a3 = MFMA(Wsig0[3], fI0, a3);
        half8 hK0 = packrelu(a0, a1), hK1 = packrelu(a2, a3);

        // ---- col0: hc = relu([x|lenc|denc] @ w_col0), K=64 ----
        a0 = z; a1 = z; a2 = z; a3 = z;
        a0 = MFMA(Wcol0[0], fI0, a0); a0 = MFMA(Wcol0[1], fI1, a0);
        a1 = MFMA(Wcol0[2], fI0, a1); a1 = MFMA(Wcol0[3], fI1, a1);
        a2 = MFMA(Wcol0[4], fI0, a2); a2 = MFMA(Wcol0[5], fI1, a2);
        a3 = MFMA(Wcol0[6], fI0, a3); a3 = MFMA(Wcol0[7], fI1, a3);
        half8 cK0 = packrelu(a0, a1), cK1 = packrelu(a2, a3);

        // ---- vis0: hv = relu([x|lenc|0] @ w_vis0), K=64 (rows 48+ zero) ----
        a0 = z; a1 = z; a2 = z; a3 = z;
        a0 = MFMA(Wvis0[0], fI0, a0); a0 = MFMA(Wvis0[1], fI1, a0);
        a1 = MFMA(Wvis0[2], fI0, a1); a1 = MFMA(Wvis0[3], fI1, a1);
        a2 = MFMA(Wvis0[4], fI0, a2); a2 = MFMA(Wvis0[5], fI1, a2);
        a3 = MFMA(Wvis0[6], fI0, a3); a3 = MFMA(Wvis0[7], fI1, a3);
        half8 vK0 = packrelu(a0, a1), vK1 = packrelu(a2, a3);

        // ---- sig1: geo = h @ w_sig1[:,1:16] (no relu), 32 padded cols ----
        a0 = z; a1 = z;
        a0 = MFMA(Wsig1[0], hK0, a0); a0 = MFMA(Wsig1[1], hK1, a0);
        a1 = MFMA(Wsig1[2], hK0, a1); a1 = MFMA(Wsig1[3], hK1, a1);
        half8 gK2 = packraw(a0, a1);

        // ---- vis1 + sigmoid: value lands at lane q==0, r=0 ----
        f32x4 av = z;
        av = MFMA(Wvis1[0], vK0, av);
        av = MFMA(Wvis1[1], vK1, av);
        float vis = 1.f / (1.f + expf(-av[0]));

        // ---- col1: h2 = relu([hc|geo] @ w_col1), K=96 padded ----
        a0 = z; a1 = z; a2 = z; a3 = z;
        a0 = MFMA(Wcol1[0], cK0, a0); a0 = MFMA(Wcol1[1], cK1, a0); a0 = MFMA(Wcol1[2], gK2, a0);
        a1 = MFMA(Wcol1[3], cK0, a1); a1 = MFMA(Wcol1[4], cK1, a1); a1 = MFMA(Wcol1[5], gK2, a1);
        a2 = MFMA(Wcol1[6], cK0, a2); a2 = MFMA(Wcol1[7], cK1, a2); a2 = MFMA(Wcol1[8], gK2, a2);
        a3 = MFMA(Wcol1[9], cK0, a3); a3 = MFMA(Wcol1[10], cK1, a3); a3 = MFMA(Wcol1[11], gK2, a3);
        half8 h2K0 = packrelu(a0, a1), h2K1 = packrelu(a2, a3);

        // ---- col2: color = relu(h2 @ w_col2) * vis; rows 0..2 at q==0 ----
        f32x4 ac = z;
        ac = MFMA(Wcol2[0], h2K0, ac);
        ac = MFMA(Wcol2[1], h2K1, ac);
        if (q == 0) {
            float* o = out + (size_t)pt * 3;
            o[0] = fmaxf(ac[0], 0.f) * vis;
            o[1] = fmaxf(ac[1], 0.f) * vis;
            o[2] = fmaxf(ac[2], 0.f) * vis;
        }
    }
}

extern "C" void kernel_launch(void* const* d_in, const int* in_sizes, int n_in,
                              void* d_out, int out_size, void* d_ws, size_t ws_size,
                              hipStream_t stream) {
    const float* x_feat = (const float*)d_in[0];
    const float* dvec   = (const float*)d_in[1];
    const float* lvec   = (const float*)d_in[2];
    const float* w_sig0 = (const float*)d_in[3];
    const float* w_sig1 = (const float*)d_in[4];
    const float* w_col0 = (const float*)d_in[5];
    const float* w_col1 = (const float*)d_in[6];
    const float* w_col2 = (const float*)d_in[7];
    const float* w_vis0 = (const float*)d_in[8];
    const float* w_vis1 = (const float*)d_in[9];
    float* out = (float*)d_out;

    const int n = in_sizes[0] / 32;   // N points (1048576: multiple of 64)
    nerf_reg<<<GRID, BLOCK, 0, stream>>>(x_feat, dvec, lvec,
                                         w_sig0, w_sig1, w_col0, w_col1,
                                         w_col2, w_vis0, w_vis1, out, n);
}